// Round 15
// baseline (201.361 us; speedup 1.0000x reference)
//
#include <hip/hip_runtime.h>
#include <hip/hip_bf16.h>

typedef int   i32x4  __attribute__((ext_vector_type(4)));
typedef int   i32x16 __attribute__((ext_vector_type(16)));
typedef unsigned int   u32;
typedef unsigned short u16;
typedef signed char    i8;

#define TOKENS 8192
#define NDIM   4096
#define KDIM   4096
#define BK     64
#define NKT    (KDIM / BK)   // 64 K-tiles

// ---------------------------------------------------------------------------
// Kernel 1 (fused, validated): blocks 0..2047 FWHT+q8 (padded-LDS transpose),
// blocks 2048..6143 qpack.  Measured ~48 us (~79% of achievable HBM BW).
// ---------------------------------------------------------------------------
__device__ __forceinline__ u32 pack4(int4 q) {
  return (u32)(q.x & 0xff) | ((u32)(q.y & 0xff) << 8) |
         ((u32)(q.z & 0xff) << 16) | ((u32)(q.w & 0xff) << 24);
}

__global__ __launch_bounds__(256)
void fused_aux(const float* __restrict__ x, i8* __restrict__ xq,
               float* __restrict__ xscale,
               const int* __restrict__ Q, i8* __restrict__ W8) {
  __shared__ float tbuf[4 * 65 * 64];

  if (blockIdx.x >= 2048) {
    const size_t idx = (((size_t)(blockIdx.x - 2048)) * 256 + threadIdx.x) * 16;
    int4 a = *reinterpret_cast<const int4*>(Q + idx);
    int4 b = *reinterpret_cast<const int4*>(Q + idx + 4);
    int4 c = *reinterpret_cast<const int4*>(Q + idx + 8);
    int4 d = *reinterpret_cast<const int4*>(Q + idx + 12);
    uint4 pk; pk.x = pack4(a); pk.y = pack4(b); pk.z = pack4(c); pk.w = pack4(d);
    *reinterpret_cast<uint4*>(W8 + idx) = pk;
    return;
  }

  const int wv  = threadIdx.x >> 6;
  const int l   = threadIdx.x & 63;
  const int row = blockIdx.x * 4 + wv;
  float* lb = tbuf + wv * (65 * 64);

  const float4* xv = reinterpret_cast<const float4*>(x + (size_t)row * KDIM) + l * 16;
  float v[64];
#pragma unroll
  for (int j = 0; j < 16; ++j) {
    float4 f = xv[j];
    v[4*j+0] = f.x; v[4*j+1] = f.y; v[4*j+2] = f.z; v[4*j+3] = f.w;
  }

#pragma unroll
  for (int h = 1; h < 64; h <<= 1) {
#pragma unroll
    for (int j = 0; j < 64; ++j) {
      if ((j & h) == 0) {
        float a = v[j], b = v[j + h];
        v[j] = a + b; v[j + h] = a - b;
      }
    }
  }

#pragma unroll
  for (int j = 0; j < 64; ++j)
    lb[l * 65 + j] = v[j];
  asm volatile("s_waitcnt lgkmcnt(0)" ::: "memory");
  __builtin_amdgcn_sched_barrier(0);
  float w[64];
#pragma unroll
  for (int j = 0; j < 64; ++j)
    w[j] = lb[j * 65 + l];

#pragma unroll
  for (int h = 1; h < 64; h <<= 1) {
#pragma unroll
    for (int j = 0; j < 64; ++j) {
      if ((j & h) == 0) {
        float a = w[j], b = w[j + h];
        w[j] = a + b; w[j + h] = a - b;
      }
    }
  }

  float mxu = 0.f;
#pragma unroll
  for (int j = 0; j < 64; ++j) mxu = fmaxf(mxu, fabsf(w[j]));
#pragma unroll
  for (int m = 1; m < 64; m <<= 1) mxu = fmaxf(mxu, __shfl_xor(mxu, m, 64));
  mxu = fmaxf(mxu, 1e-30f);
  const float inv = 127.0f / mxu;

  i8* orow = xq + (size_t)row * KDIM + l;
#pragma unroll
  for (int j = 0; j < 64; ++j) {
    int b = __float2int_rn(w[j] * inv);
    b = min(127, max(-127, b));
    orow[j * 64] = (i8)b;
  }
  if (l == 0) xscale[row] = mxu * (0.015625f / 127.0f);
}

// ---------------------------------------------------------------------------
// Kernel 2: int8 GEMM with 32x32x32 MFMA (4404 vs 3944 TOPS, half the
// instruction count). R6's validated pipeline skeleton verbatim (ring-4,
// vmcnt(4/2/0), lgkm(6) counted waits, one barrier/tile, setprio).
// New conflict-free swizzle for 32-row fragment reads:
//   phys_col = col ^ (((row>>1)&3)<<4)  -> bank-group g = row&7 (balanced).
// Staging pre-swizzles the GLOBAL source col with the same involution.
// Per wave 128x64 tile = 4(m) x 2(n) blocks of 32x32; acc i32x16[4][2].
// Fragment: lane l -> row (l&31), k-half (l>>5); C/D per m74: col=lane&31,
// row=(reg&3)+8*(reg>>2)+4*(lane>>5).
// ---------------------------------------------------------------------------
__global__ __launch_bounds__(512, 2)
void gemm32_i8(const i8* __restrict__ A, const i8* __restrict__ B,
               const float* __restrict__ xscale, const float* __restrict__ s,
               const float* __restrict__ bias, float* __restrict__ C) {
  __shared__ __align__(16) i8 lds[4 * 32768];   // 128 KB

  const int th   = threadIdx.x;
  const int wave = th >> 6;
  const int lane = th & 63;

  const int b0 = blockIdx.x;
  const int xc = b0 & 7;
  const int i  = b0 >> 3;
  const int mt = i >> 1;
  const int nt = xc * 2 + (i & 1);

  // staging: pre-swizzled global col (matches read-side XOR involution)
  const int srow = th >> 2;
  const int scol = ((th & 3) * 16) ^ (((th >> 3) & 3) << 4);
  const i8* gA0 = A + (size_t)(mt * 256 + srow) * KDIM + scol;
  const i8* gA1 = gA0 + (size_t)128 * KDIM;
  const i8* gB0 = B + (size_t)(nt * 256 + srow) * KDIM + scol;
  const i8* gB1 = gB0 + (size_t)128 * KDIM;

  const int ldsA0 = wave * 1024;
  const int ldsA1 = 8192 + wave * 1024;
  const int ldsB0 = 16384 + wave * 1024;
  const int ldsB1 = 24576 + wave * 1024;

#define STAGE_A(tt, ss) do {                                                    \
    __builtin_amdgcn_global_load_lds(                                           \
      (const __attribute__((address_space(1))) void*)(gA0 + (size_t)(tt) * BK), \
      (__attribute__((address_space(3))) void*)(lds + (ss) * 32768 + ldsA0), 16, 0, 0); \
    __builtin_amdgcn_global_load_lds(                                           \
      (const __attribute__((address_space(1))) void*)(gA1 + (size_t)(tt) * BK), \
      (__attribute__((address_space(3))) void*)(lds + (ss) * 32768 + ldsA1), 16, 0, 0); \
  } while (0)
#define STAGE_B(tt, ss) do {                                                    \
    __builtin_amdgcn_global_load_lds(                                           \
      (const __attribute__((address_space(1))) void*)(gB0 + (size_t)(tt) * BK), \
      (__attribute__((address_space(3))) void*)(lds + (ss) * 32768 + ldsB0), 16, 0, 0); \
    __builtin_amdgcn_global_load_lds(                                           \
      (const __attribute__((address_space(1))) void*)(gB1 + (size_t)(tt) * BK), \
      (__attribute__((address_space(3))) void*)(lds + (ss) * 32768 + ldsB1), 16, 0, 0); \
  } while (0)

  // fragment addressing (32x32): row = l&31 (+mb*32 / +nb*32), k-half = l>>5
  const int wm  = wave >> 2;       // 0..1 -> C rows wm*128
  const int wn  = wave & 3;        // 0..3 -> C cols wn*64
  const int l31 = lane & 31;
  const int lh  = lane >> 5;
  const int swz = ((l31 >> 1) & 3) << 4;
  const int colK0 = (lh * 16) ^ swz;          // kk=0 quarter
  const int colK1 = (32 + lh * 16) ^ swz;     // kk=1 quarter
  const int aBase = (wm * 128 + l31) * 64;            // + mb*2048
  const int bBase = (wn * 64  + l31) * 64 + 16384;    // + nb*2048

  i32x16 acc[4][2];
#pragma unroll
  for (int mb = 0; mb < 4; ++mb)
#pragma unroll
    for (int nb = 0; nb < 2; ++nb)
#pragma unroll
      for (int r = 0; r < 16; ++r)
        acc[mb][nb][r] = 0;

  // prologue: stage tiles 0,1; wait tile 0; preload tile-0 kk0 fragments
  STAGE_A(0, 0); STAGE_B(0, 0);
  STAGE_A(1, 1); STAGE_B(1, 1);
  asm volatile("s_waitcnt vmcnt(4)" ::: "memory");
  __builtin_amdgcn_sched_barrier(0);
  __builtin_amdgcn_s_barrier();

  i32x4 aK0[4], bK0[2], aK1[4], bK1[2];
  {
    const char* c0 = (const char*)lds;
#pragma unroll
    for (int nb = 0; nb < 2; ++nb)
      bK0[nb] = *(const i32x4*)(c0 + bBase + nb * 2048 + colK0);
#pragma unroll
    for (int mb = 0; mb < 4; ++mb)
      aK0[mb] = *(const i32x4*)(c0 + aBase + mb * 2048 + colK0);
  }

  for (int t = 0; t < NKT; ++t) {
    const char* cur = (const char*)lds + (t & 3) * 32768;
    const char* nxt = (const char*)lds + ((t + 1) & 3) * 32768;

    // ---- kk1 reads fly under kk0 MFMA
#pragma unroll
    for (int nb = 0; nb < 2; ++nb)
      bK1[nb] = *(const i32x4*)(cur + bBase + nb * 2048 + colK1);
#pragma unroll
    for (int mb = 0; mb < 4; ++mb)
      aK1[mb] = *(const i32x4*)(cur + aBase + mb * 2048 + colK1);
    if (t + 2 < NKT) STAGE_A(t + 2, (t + 2) & 3);
    asm volatile("s_waitcnt lgkmcnt(6)" ::: "memory");   // kk0 frags ready
    __builtin_amdgcn_sched_barrier(0);
    __builtin_amdgcn_s_setprio(1);
#pragma unroll
    for (int mb = 0; mb < 4; ++mb)
#pragma unroll
      for (int nb = 0; nb < 2; ++nb)
        acc[mb][nb] = __builtin_amdgcn_mfma_i32_32x32x32_i8(aK0[mb], bK0[nb], acc[mb][nb], 0, 0, 0);
    __builtin_amdgcn_s_setprio(0);

    if (t + 2 < NKT)      { asm volatile("s_waitcnt vmcnt(2)" ::: "memory"); }
    else if (t + 1 < NKT) { asm volatile("s_waitcnt vmcnt(0)" ::: "memory"); }
    __builtin_amdgcn_sched_barrier(0);
    if (t + 1 < NKT) {
      __builtin_amdgcn_s_barrier();                      // tile t+1 staged
#pragma unroll
      for (int nb = 0; nb < 2; ++nb)
        bK0[nb] = *(const i32x4*)(nxt + bBase + nb * 2048 + colK0);
#pragma unroll
      for (int mb = 0; mb < 4; ++mb)
        aK0[mb] = *(const i32x4*)(nxt + aBase + mb * 2048 + colK0);
      if (t + 2 < NKT) STAGE_B(t + 2, (t + 2) & 3);
      asm volatile("s_waitcnt lgkmcnt(6)" ::: "memory"); // kk1 frags ready
      __builtin_amdgcn_sched_barrier(0);
    } else {
      asm volatile("s_waitcnt lgkmcnt(0)" ::: "memory");
      __builtin_amdgcn_sched_barrier(0);
    }
    __builtin_amdgcn_s_setprio(1);
#pragma unroll
    for (int mb = 0; mb < 4; ++mb)
#pragma unroll
      for (int nb = 0; nb < 2; ++nb)
        acc[mb][nb] = __builtin_amdgcn_mfma_i32_32x32x32_i8(aK1[mb], bK1[nb], acc[mb][nb], 0, 0, 0);
    __builtin_amdgcn_s_setprio(0);
  }
#undef STAGE_A
#undef STAGE_B

  // epilogue: C/D mapping (m74): col = lane&31, row = (reg&3)+8*(reg>>2)+4*lh
  const int col0 = nt * 256 + wn * 64 + l31;
  const int row0 = mt * 256 + wm * 128 + lh * 4;
#pragma unroll
  for (int nb = 0; nb < 2; ++nb) {
    const int colb = col0 + nb * 32;
    const float sc = s[colb];
    const float bv = bias[colb];
#pragma unroll
    for (int mb = 0; mb < 4; ++mb) {
#pragma unroll
      for (int q = 0; q < 4; ++q) {
        const int rbase = row0 + mb * 32 + q * 8;
#pragma unroll
        for (int r = 0; r < 4; ++r) {
          const int row = rbase + r;
          C[(size_t)row * NDIM + colb] =
              (float)acc[mb][nb][q * 4 + r] * (xscale[row] * sc) + bv;
        }
      }
    }
  }
}

// ---------------------------------------------------------------------------
extern "C" void kernel_launch(void* const* d_in, const int* in_sizes, int n_in,
                              void* d_out, int out_size, void* d_ws, size_t ws_size,
                              hipStream_t stream) {
  (void)in_sizes; (void)n_in; (void)out_size; (void)ws_size;
  const float* x    = (const float*)d_in[0];
  const int*   Q    = (const int*)d_in[1];
  const float* s    = (const float*)d_in[2];
  const float* bias = (const float*)d_in[3];
  float* out = (float*)d_out;

  i8*    xq     = (i8*)d_ws;
  i8*    W8     = xq + (size_t)TOKENS * KDIM;
  float* xscale = (float*)(W8 + (size_t)NDIM * KDIM);

  fused_aux<<<dim3(6144), dim3(256), 0, stream>>>(x, xq, xscale, Q, W8);
  gemm32_i8<<<dim3((TOKENS / 256) * (NDIM / 256)), dim3(512), 0, stream>>>(
      xq, W8, xscale, s, bias, out);
}

// Round 16
// 192.387 us; speedup vs baseline: 1.0466x; 1.0466x over previous
//
#include <hip/hip_runtime.h>
#include <hip/hip_bf16.h>

typedef int   i32x4 __attribute__((ext_vector_type(4)));
typedef unsigned int   u32;
typedef unsigned short u16;
typedef signed char    i8;

#define TOKENS 8192
#define NDIM   4096
#define KDIM   4096
#define BK     64
#define NKT    (KDIM / BK)   // 64 K-tiles

// ---------------------------------------------------------------------------
// Kernel 1 (fused): blocks 0..2047 = FWHT+q8 (4 rows/block, 1 wave/row),
// blocks 2048..6143 = qpack.
// FWHT stage-order swapped (stages commute): lane l owns e = j*64+l ->
// coalesced scalar loads; bits 6..11 in-register; padded-LDS transpose
// ((l+j)%32 banks, 2-way = free); bits 0..5 in-register; lane then owns a
// CONTIGUOUS 64-elem chunk -> absmax + 4x uint4 packed stores (16B/lane).
// ---------------------------------------------------------------------------
__device__ __forceinline__ u32 pack4(int4 q) {
  return (u32)(q.x & 0xff) | ((u32)(q.y & 0xff) << 8) |
         ((u32)(q.z & 0xff) << 16) | ((u32)(q.w & 0xff) << 24);
}

__global__ __launch_bounds__(256)
void fused_aux(const float* __restrict__ x, i8* __restrict__ xq,
               float* __restrict__ xscale,
               const int* __restrict__ Q, i8* __restrict__ W8) {
  __shared__ float tbuf[4 * 65 * 64];

  if (blockIdx.x >= 2048) {
    // ---- qpack ----
    const size_t idx = (((size_t)(blockIdx.x - 2048)) * 256 + threadIdx.x) * 16;
    int4 a = *reinterpret_cast<const int4*>(Q + idx);
    int4 b = *reinterpret_cast<const int4*>(Q + idx + 4);
    int4 c = *reinterpret_cast<const int4*>(Q + idx + 8);
    int4 d = *reinterpret_cast<const int4*>(Q + idx + 12);
    uint4 pk; pk.x = pack4(a); pk.y = pack4(b); pk.z = pack4(c); pk.w = pack4(d);
    *reinterpret_cast<uint4*>(W8 + idx) = pk;
    return;
  }

  const int wv  = threadIdx.x >> 6;
  const int l   = threadIdx.x & 63;
  const int row = blockIdx.x * 4 + wv;
  float* lb = tbuf + wv * (65 * 64);

  // coalesced load: inst j reads x[row][j*64 + l] (lanes contiguous)
  const float* xrow = x + (size_t)row * KDIM;
  float v[64];
#pragma unroll
  for (int j = 0; j < 64; ++j)
    v[j] = xrow[j * 64 + l];
  // lane l owns elements e = j*64 + l; bits 6..11 of e = j -> in-register

#pragma unroll
  for (int h = 1; h < 64; h <<= 1) {
#pragma unroll
    for (int j = 0; j < 64; ++j) {
      if ((j & h) == 0) {
        float a = v[j], b = v[j + h];
        v[j] = a + b; v[j + h] = a - b;
      }
    }
  }

  // transpose: cell (l,j) <- elem j*64+l; read (j,l) -> lane owns e = l*64+j
#pragma unroll
  for (int j = 0; j < 64; ++j)
    lb[l * 65 + j] = v[j];
  asm volatile("s_waitcnt lgkmcnt(0)" ::: "memory");
  __builtin_amdgcn_sched_barrier(0);
  float w[64];
#pragma unroll
  for (int j = 0; j < 64; ++j)
    w[j] = lb[j * 65 + l];

  // bits 0..5 of e = j -> in-register
#pragma unroll
  for (int h = 1; h < 64; h <<= 1) {
#pragma unroll
    for (int j = 0; j < 64; ++j) {
      if ((j & h) == 0) {
        float a = w[j], b = w[j + h];
        w[j] = a + b; w[j + h] = a - b;
      }
    }
  }

  float mxu = 0.f;
#pragma unroll
  for (int j = 0; j < 64; ++j) mxu = fmaxf(mxu, fabsf(w[j]));
#pragma unroll
  for (int m = 1; m < 64; m <<= 1) mxu = fmaxf(mxu, __shfl_xor(mxu, m, 64));
  mxu = fmaxf(mxu, 1e-30f);
  const float inv = 127.0f / mxu;

  // lane owns e = l*64 + j (contiguous 64) -> packed 16B stores
  i8* orow = xq + (size_t)row * KDIM + l * 64;
#pragma unroll
  for (int g = 0; g < 4; ++g) {
    u32 wd[4];
#pragma unroll
    for (int q4 = 0; q4 < 4; ++q4) {
      int b0 = __float2int_rn(w[g*16+q4*4+0] * inv);
      int b1 = __float2int_rn(w[g*16+q4*4+1] * inv);
      int b2 = __float2int_rn(w[g*16+q4*4+2] * inv);
      int b3 = __float2int_rn(w[g*16+q4*4+3] * inv);
      b0 = min(127, max(-127, b0)); b1 = min(127, max(-127, b1));
      b2 = min(127, max(-127, b2)); b3 = min(127, max(-127, b3));
      wd[q4] = (u32)(b0 & 0xff) | ((u32)(b1 & 0xff) << 8) |
               ((u32)(b2 & 0xff) << 16) | ((u32)(b3 & 0xff) << 24);
    }
    uint4 pk; pk.x = wd[0]; pk.y = wd[1]; pk.z = wd[2]; pk.w = wd[3];
    *reinterpret_cast<uint4*>(orow + g * 16) = pk;
  }
  if (l == 0) xscale[row] = mxu * (0.015625f / 127.0f);
}

// ---------------------------------------------------------------------------
// Kernel 2: int8 GEMM — R6 register-pipeline kernel VERBATIM (best measured,
// 143-146 us band; 9 structural variants failed to beat it).
// ---------------------------------------------------------------------------
__global__ __launch_bounds__(512, 2)
void gemm256_i8(const i8* __restrict__ A, const i8* __restrict__ B,
                const float* __restrict__ xscale, const float* __restrict__ s,
                const float* __restrict__ bias, float* __restrict__ C) {
  __shared__ __align__(16) i8 lds[4 * 32768];   // 128 KB

  const int th   = threadIdx.x;
  const int wave = th >> 6;
  const int lane = th & 63;

  const int b0 = blockIdx.x;
  const int xc = b0 & 7;
  const int i  = b0 >> 3;
  const int mt = i >> 1;
  const int nt = xc * 2 + (i & 1);

  const int srow = th >> 2;
  const int scol = ((th & 3) * 16) ^ (((th >> 5) & 1) << 5);
  const i8* gA0 = A + (size_t)(mt * 256 + srow) * KDIM + scol;
  const i8* gA1 = gA0 + (size_t)128 * KDIM;
  const i8* gB0 = B + (size_t)(nt * 256 + srow) * KDIM + scol;
  const i8* gB1 = gB0 + (size_t)128 * KDIM;

  const int ldsA0 = wave * 1024;
  const int ldsA1 = 8192 + wave * 1024;
  const int ldsB0 = 16384 + wave * 1024;
  const int ldsB1 = 24576 + wave * 1024;

#define STAGE_A(tt, ss) do {                                                    \
    __builtin_amdgcn_global_load_lds(                                           \
      (const __attribute__((address_space(1))) void*)(gA0 + (size_t)(tt) * BK), \
      (__attribute__((address_space(3))) void*)(lds + (ss) * 32768 + ldsA0), 16, 0, 0); \
    __builtin_amdgcn_global_load_lds(                                           \
      (const __attribute__((address_space(1))) void*)(gA1 + (size_t)(tt) * BK), \
      (__attribute__((address_space(3))) void*)(lds + (ss) * 32768 + ldsA1), 16, 0, 0); \
  } while (0)
#define STAGE_B(tt, ss) do {                                                    \
    __builtin_amdgcn_global_load_lds(                                           \
      (const __attribute__((address_space(1))) void*)(gB0 + (size_t)(tt) * BK), \
      (__attribute__((address_space(3))) void*)(lds + (ss) * 32768 + ldsB0), 16, 0, 0); \
    __builtin_amdgcn_global_load_lds(                                           \
      (const __attribute__((address_space(1))) void*)(gB1 + (size_t)(tt) * BK), \
      (__attribute__((address_space(3))) void*)(lds + (ss) * 32768 + ldsB1), 16, 0, 0); \
  } while (0)

  const int wm = wave >> 2;
  const int wn = wave & 3;
  const int laneRow = lane & 15;
  const int kByte   = (lane >> 4) << 4;
  const int swz     = ((lane >> 3) & 1) << 5;
  const int aOff = (((wm * 128 + laneRow) * 64 + kByte) ^ swz);
  const int bOff = (((wn * 64 + laneRow) * 64 + kByte) ^ swz) + 16384;

  i32x4 acc[8][4];
#pragma unroll
  for (int mi = 0; mi < 8; ++mi)
#pragma unroll
    for (int ni = 0; ni < 4; ++ni)
      acc[mi][ni] = i32x4{0, 0, 0, 0};

  STAGE_A(0, 0); STAGE_B(0, 0);
  STAGE_A(1, 1); STAGE_B(1, 1);
  asm volatile("s_waitcnt vmcnt(4)" ::: "memory");
  __builtin_amdgcn_sched_barrier(0);
  __builtin_amdgcn_s_barrier();

  i32x4 afA[4], afB[4], bf0[4], bf1[4];
  {
    const char* c0 = (const char*)lds;
#pragma unroll
    for (int ni = 0; ni < 4; ++ni)
      bf0[ni] = *(const i32x4*)(c0 + bOff + ni * 1024);
#pragma unroll
    for (int mi = 0; mi < 4; ++mi)
      afA[mi] = *(const i32x4*)(c0 + aOff + mi * 1024);
  }

#define TILE(t, BFC, BFN) do {                                                  \
    const char* cur = (const char*)lds + ((t) & 3) * 32768;                     \
    const char* nxt = (const char*)lds + (((t) + 1) & 3) * 32768;               \
    _Pragma("unroll")                                                           \
    for (int mi = 0; mi < 4; ++mi)                                              \
      afB[mi] = *(const i32x4*)(cur + aOff + 4096 + mi * 1024);                 \
    if ((t) + 2 < NKT) STAGE_A((t) + 2, ((t) + 2) & 3);                         \
    asm volatile("s_waitcnt lgkmcnt(4)" ::: "memory");                          \
    __builtin_amdgcn_sched_barrier(0);                                          \
    __builtin_amdgcn_s_setprio(1);                                              \
    _Pragma("unroll")                                                           \
    for (int mi = 0; mi < 4; ++mi)                                              \
      _Pragma("unroll")                                                         \
      for (int ni = 0; ni < 4; ++ni)                                            \
        acc[mi][ni] = __builtin_amdgcn_mfma_i32_16x16x64_i8(afA[mi], BFC[ni],   \
                                                            acc[mi][ni], 0, 0, 0); \
    __builtin_amdgcn_s_setprio(0);                                              \
    if ((t) + 1 < NKT) {                                                        \
      if ((t) + 2 < NKT) { asm volatile("s_waitcnt vmcnt(2)" ::: "memory"); }   \
      else               { asm volatile("s_waitcnt vmcnt(0)" ::: "memory"); }   \
      __builtin_amdgcn_sched_barrier(0);                                        \
      __builtin_amdgcn_s_barrier();                                             \
      _Pragma("unroll")                                                         \
      for (int ni = 0; ni < 4; ++ni)                                            \
        BFN[ni] = *(const i32x4*)(nxt + bOff + ni * 1024);                      \
      _Pragma("unroll")                                                         \
      for (int mi = 0; mi < 4; ++mi)                                            \
        afA[mi] = *(const i32x4*)(nxt + aOff + mi * 1024);                      \
      if ((t) + 2 < NKT) STAGE_B((t) + 2, ((t) + 2) & 3);                       \
      asm volatile("s_waitcnt lgkmcnt(8)" ::: "memory");                        \
      __builtin_amdgcn_sched_barrier(0);                                        \
    } else {                                                                    \
      asm volatile("s_waitcnt lgkmcnt(0)" ::: "memory");                        \
      __builtin_amdgcn_sched_barrier(0);                                        \
    }                                                                           \
    __builtin_amdgcn_s_setprio(1);                                              \
    _Pragma("unroll")                                                           \
    for (int mi = 0; mi < 4; ++mi)                                              \
      _Pragma("unroll")                                                         \
      for (int ni = 0; ni < 4; ++ni)                                            \
        acc[mi + 4][ni] = __builtin_amdgcn_mfma_i32_16x16x64_i8(afB[mi], BFC[ni], \
                                                            acc[mi + 4][ni], 0, 0, 0); \
    __builtin_amdgcn_s_setprio(0);                                              \
  } while (0)

  for (int t = 0; t < NKT; t += 2) {
    TILE(t,     bf0, bf1);
    TILE(t + 1, bf1, bf0);
  }
#undef TILE
#undef STAGE_A
#undef STAGE_B

  const int col0 = nt * 256 + wn * 64 + (lane & 15);
  const int row0 = mt * 256 + wm * 128 + ((lane >> 4) << 2);
  float xs[4][8];
#pragma unroll
  for (int mi = 0; mi < 8; ++mi)
#pragma unroll
    for (int r = 0; r < 4; ++r)
      xs[r][mi] = xscale[row0 + mi * 16 + r];
#pragma unroll
  for (int ni = 0; ni < 4; ++ni) {
    const float sc = s[col0 + ni * 16];
    const float bv = bias[col0 + ni * 16];
#pragma unroll
    for (int mi = 0; mi < 8; ++mi) {
      float* cp = C + (size_t)(row0 + mi * 16) * NDIM + col0 + ni * 16;
#pragma unroll
      for (int r = 0; r < 4; ++r)
        cp[(size_t)r * NDIM] = (float)acc[mi][ni][r] * (xs[r][mi] * sc) + bv;
    }
  }
}

// ---------------------------------------------------------------------------
extern "C" void kernel_launch(void* const* d_in, const int* in_sizes, int n_in,
                              void* d_out, int out_size, void* d_ws, size_t ws_size,
                              hipStream_t stream) {
  (void)in_sizes; (void)n_in; (void)out_size; (void)ws_size;
  const float* x    = (const float*)d_in[0];
  const int*   Q    = (const int*)d_in[1];
  const float* s    = (const float*)d_in[2];
  const float* bias = (const float*)d_in[3];
  float* out = (float*)d_out;

  i8*    xq     = (i8*)d_ws;
  i8*    W8     = xq + (size_t)TOKENS * KDIM;
  float* xscale = (float*)(W8 + (size_t)NDIM * KDIM);

  fused_aux<<<dim3(6144), dim3(256), 0, stream>>>(x, xq, xscale, Q, W8);
  gemm256_i8<<<dim3((TOKENS / 256) * (NDIM / 256)), dim3(512), 0, stream>>>(
      xq, W8, xscale, s, bias, out);
}